// Round 8
// baseline (1412.054 us; speedup 1.0000x reference)
//
#include <hip/hip_runtime.h>

// PCmer forward: bf16-MFMA; phi_k fused INTO ctx (64-token chunks); phi_q+dinv+attn_out fused
// (ctxbT staged via async cp); GLU fused into pw1; fused QKV; BN=64 GEMM tiles for N=512.
// L=6, B=4, N=2048, D=512, H=8, DH=64, ID=512, M=266, INNER=1024, K=31.

#define L_LAYERS 6
#define B_ 4
#define N_ 2048
#define D_ 512
#define H_ 8
#define DH_ 64
#define M_ 266
#define INNER_ 1024
#define T_ 8192
#define PS_ 320            // padded m stride (zeros in [266,320))
#define QKVS_ 1536         // qkv row stride
#define NS_ 4              // ctx n-splits

typedef __attribute__((ext_vector_type(8))) short short8;
typedef __attribute__((ext_vector_type(4))) float floatx4;

__device__ __forceinline__ ushort f2bf(float f) {
  union { float f; uint u; } v; v.f = f;
  uint r = v.u + 0x7fffu + ((v.u >> 16) & 1u);
  return (ushort)(r >> 16);
}
__device__ __forceinline__ float bf2f(ushort u) {
  union { uint u; float f; } v; v.u = ((uint)u) << 16;
  return v.f;
}
__device__ __forceinline__ float wave_sum(float v) {
#pragma unroll
  for (int m = 1; m < 64; m <<= 1) v += __shfl_xor(v, m);
  return v;
}
__device__ __forceinline__ void async_cp16(const void* g, void* l) {
  __builtin_amdgcn_global_load_lds(
      (const __attribute__((address_space(1))) void*)g,
      (__attribute__((address_space(3))) void*)l, 16, 0, 0);
}

// ---------------- weight packing ----------------
__global__ void f2bf4_kernel(const float4* __restrict__ in, ushort* __restrict__ out, int n4) {
  int i = blockIdx.x * 256 + threadIdx.x;
  if (i < n4) {
    float4 v = in[i];
    ushort4 r;
    r.x = f2bf(v.x); r.y = f2bf(v.y); r.z = f2bf(v.z); r.w = f2bf(v.w);
    *(ushort4*)(out + (size_t)i * 4) = r;
  }
}
__global__ void pack_qkv_w(const float4* __restrict__ src, ushort* __restrict__ dst, int off) {
  int i = blockIdx.x * 256 + threadIdx.x;   // L*512*128
  if (i >= L_LAYERS * 512 * 128) return;
  int l = i >> 16;
  int rem = i & 65535;
  int row = rem >> 7, c4 = rem & 127;
  float4 v = src[i];
  ushort4 r;
  r.x = f2bf(v.x); r.y = f2bf(v.y); r.z = f2bf(v.z); r.w = f2bf(v.w);
  *(ushort4*)(dst + ((size_t)l * QKVS_ + off + row) * 512 + c4 * 4) = r;
}
__global__ void pack_qkv_b(const float* __restrict__ bq, const float* __restrict__ bk,
                           const float* __restrict__ bv, float* __restrict__ dst) {
  int i = blockIdx.x * 256 + threadIdx.x;
  if (i >= L_LAYERS * QKVS_) return;
  int l = i / QKVS_, c = i % QKVS_;
  dst[i] = c < 512 ? bq[l * 512 + c] : (c < 1024 ? bk[l * 512 + c - 512] : bv[l * 512 + c - 1024]);
}
__global__ void pad_proj(const float* __restrict__ proj, ushort* __restrict__ dst) {
  int i = blockIdx.x * 256 + threadIdx.x;   // L*320*64
  if (i >= L_LAYERS * 320 * 64) return;
  int l = i / (320 * 64), rem = i % (320 * 64), m = rem >> 6, kk = rem & 63;
  dst[i] = (m < M_) ? f2bf(proj[((size_t)l * M_ + m) * 64 + kk]) : (ushort)0;
}
__global__ void pack_pw1_w(const float4* __restrict__ src, ushort* __restrict__ dst) {
  int i = blockIdx.x * 256 + threadIdx.x;   // L*2048*128
  if (i >= L_LAYERS * 2048 * 128) return;
  int l = i >> 18;
  int rem = i & 262143;
  int cp = rem >> 7, c4 = rem & 127;
  int s = (cp >> 4) & 1;
  int srow = ((cp >> 5) << 4) + (cp & 15) + s * 1024;
  float4 v = src[((size_t)l * 2048 + srow) * 128 + c4];
  ushort4 r;
  r.x = f2bf(v.x); r.y = f2bf(v.y); r.z = f2bf(v.z); r.w = f2bf(v.w);
  *(ushort4*)(dst + ((size_t)l * 2048 + cp) * 512 + c4 * 4) = r;
}
__global__ void pack_pw1_b(const float* __restrict__ src, float* __restrict__ dst) {
  int i = blockIdx.x * 256 + threadIdx.x;
  if (i >= L_LAYERS * 2048) return;
  int l = i >> 11, cp = i & 2047;
  int s = (cp >> 4) & 1;
  int srow = ((cp >> 5) << 4) + (cp & 15) + s * 1024;
  dst[i] = src[l * 2048 + srow];
}

// ---------------- layernorm ----------------
__global__ __launch_bounds__(256) void ln_kernel(const float* __restrict__ x,
                                                 const float* __restrict__ g,
                                                 const float* __restrict__ b,
                                                 ushort* __restrict__ out) {
  const int t = blockIdx.x;
  const int tid = threadIdx.x;
  const float* row = x + (size_t)t * D_;
  float v0 = row[tid], v1 = row[tid + 256];
  float s1 = v0 + v1;
  float s2 = v0 * v0 + v1 * v1;
  s1 = wave_sum(s1);
  s2 = wave_sum(s2);
  __shared__ float sh1[4], sh2[4];
  int w = tid >> 6;
  if ((tid & 63) == 0) { sh1[w] = s1; sh2[w] = s2; }
  __syncthreads();
  s1 = sh1[0] + sh1[1] + sh1[2] + sh1[3];
  s2 = sh2[0] + sh2[1] + sh2[2] + sh2[3];
  float mu = s1 * (1.f / D_);
  float var = s2 * (1.f / D_) - mu * mu;
  float rs = rsqrtf(var + 1e-5f);
  out[(size_t)t * D_ + tid]       = f2bf((v0 - mu) * rs * g[tid] + b[tid]);
  out[(size_t)t * D_ + tid + 256] = f2bf((v1 - mu) * rs * g[tid + 256] + b[tid + 256]);
}

// ---------------- bf16 MFMA GEMM, tile 128 x BN (BN = 128 or 64) ----------------
template <bool HAS_RES, bool OUT_BF16, int ACT, int BN>
__global__ __launch_bounds__(256) void gemm_mfma(const ushort* __restrict__ A,
                                                 const ushort* __restrict__ W,
                                                 const float* __restrict__ bias,
                                                 const float* __restrict__ res,
                                                 void* __restrict__ Cout,
                                                 int K, int ldc) {
  constexpr int NJ = BN / 32;       // B-frags per wave (4 or 2)
  __shared__ ushort As[128 * 32];
  __shared__ ushort Bs[BN * 32];
  const int tid = threadIdx.x;
  const int w = tid >> 6, lane = tid & 63;
  const int row0 = blockIdx.x * 128, col0 = blockIdx.y * BN;
  const int rl = lane >> 2;
  const int lc = ((lane & 3) ^ ((lane >> 3) & 3)) * 8;
  const ushort* gA0 = A + (size_t)(row0 + w * 32 + rl) * K + lc;
  const ushort* gA1 = gA0 + (size_t)16 * K;
  const ushort* gB0 = W + (size_t)(col0 + w * (BN / 4) + rl) * K + lc;
  const ushort* gB1 = gB0 + (size_t)16 * K;   // used only for BN=128
  ushort* lA = As + w * 1024;
  ushort* lB = Bs + w * (BN * 8);
  const int m16 = lane & 15, quad = lane >> 4;
  const int awr = (w >> 1) * 64, bwc = (w & 1) * (BN / 2);
  floatx4 acc[4][NJ] = {};
  for (int k0 = 0; k0 < K; k0 += 32) {
    __syncthreads();
    async_cp16(gA0 + k0, lA);
    async_cp16(gA1 + k0, lA + 512);
    async_cp16(gB0 + k0, lB);
    if (BN == 128) async_cp16(gB1 + k0, lB + 512);
    __syncthreads();
    short8 af[4], bfr[NJ];
#pragma unroll
    for (int i = 0; i < 4; i++) {
      int r = awr + i * 16 + m16;
      af[i] = *(const short8*)&As[r * 32 + (quad ^ ((r >> 1) & 3)) * 8];
    }
#pragma unroll
    for (int j = 0; j < NJ; j++) {
      int r = bwc + j * 16 + m16;
      bfr[j] = *(const short8*)&Bs[r * 32 + (quad ^ ((r >> 1) & 3)) * 8];
    }
#pragma unroll
    for (int i = 0; i < 4; i++)
#pragma unroll
      for (int j = 0; j < NJ; j++)
        acc[i][j] = __builtin_amdgcn_mfma_f32_16x16x32_bf16(af[i], bfr[j], acc[i][j], 0, 0, 0);
  }
  if (ACT == 0) {
#pragma unroll
    for (int i = 0; i < 4; i++) {
      const int r0 = row0 + awr + i * 16 + quad * 4;
#pragma unroll
      for (int j = 0; j < NJ; j++) {
        const int c = col0 + bwc + j * 16 + m16;
        const float bv = bias[c];
#pragma unroll
        for (int r = 0; r < 4; r++) {
          float vv = acc[i][j][r] + bv;
          if (HAS_RES) vv += res[(size_t)(r0 + r) * ldc + c];
          if (OUT_BF16) ((ushort*)Cout)[(size_t)(r0 + r) * ldc + c] = f2bf(vv);
          else          ((float*)Cout)[(size_t)(r0 + r) * ldc + c] = vv;
        }
      }
    }
  } else {
    // GLU epilogue (BN=128 only): interleaved a/g 16-col blocks
#pragma unroll
    for (int i = 0; i < 4; i++) {
      const int r0 = row0 + awr + i * 16 + quad * 4;
#pragma unroll
      for (int jp = 0; jp < NJ / 2; jp++) {
        const int j = jp * 2;
        const int ca = col0 + bwc + j * 16 + m16;
        const float ba = bias[ca], bg = bias[ca + 16];
        const int oc = ((col0 + bwc) >> 1) + jp * 16 + m16;
#pragma unroll
        for (int r = 0; r < 4; r++) {
          float a = acc[i][j][r] + ba;
          float g = acc[i][j + 1][r] + bg;
          float z = a / (1.f + expf(-g));
          ((ushort*)Cout)[(size_t)(r0 + r) * ldc + oc] = f2bf(z);
        }
      }
    }
  }
}

// ---------------- ctx with phi_k fused: 64-token chunks ----------------
// grid (bh=32, mt=5, ns=NS_). part[bh][ns][mt][64m][64e]; kpart[bh][ns][mt][64m].
__global__ __launch_bounds__(256) void ctx_phi_mfma(const ushort* __restrict__ qkv,
                                                    const ushort* __restrict__ projp,
                                                    float* __restrict__ part,
                                                    float* __restrict__ kpart) {
  __shared__ ushort projs[64 * 64];  // proj rows m0..m0+63, XOR-8 chunks
  __shared__ ushort kts[64 * 64];    // raw k tile (64 tokens), XOR-8 chunks
  __shared__ ushort kps[64][72];     // phi^T [m][n], XOR-8 swizzle
  __shared__ ushort vsT[64][72];     // v^T  [e][n], XOR-8 swizzle
  __shared__ float diag_sh[64];
  __shared__ float kshare[4][64];
  const int bh = blockIdx.x, mt = blockIdx.y, ns = blockIdx.z;
  const int b = bh >> 3, h = bh & 7;
  const int m0 = mt * 64;
  const int tid = threadIdx.x;
  const int w = tid >> 6, lane = tid & 63, l16 = lane & 15, quad = lane >> 4;
  const int rl8 = lane >> 3;
  const int lc8 = ((lane & 7) ^ (rl8 & 7)) * 8;
  // stage proj slice once
#pragma unroll
  for (int j = 0; j < 2; j++) {
    const int rb = w * 16 + j * 8;
    async_cp16(projp + (size_t)(m0 + rb + rl8) * 64 + lc8, projs + rb * 64);
  }
  const int nn = tid >> 3;   // 0..31 (and +32)
  const int a8 = tid & 7;    // e-octet
  const int km = tid & 63, kg = tid >> 6;
  const float dn = 0.35355339059327373f;
  const float ratio = 0.06131393394849658f;
  floatx4 acc[4] = {};
  float ksp = 0.f;
  for (int nstep = 0; nstep < 2048 / NS_ / 64; nstep++) {
    const int n0 = ns * (2048 / NS_) + nstep * 64;
    // stage raw k tile (64 tokens x 64 dh)
#pragma unroll
    for (int j = 0; j < 2; j++) {
      const int rb = w * 16 + j * 8;
      async_cp16(qkv + (size_t)(b * N_ + n0 + rb + rl8) * QKVS_ + 512 + h * 64 + lc8,
                 kts + rb * 64);
    }
    uint4 vv0 = *(const uint4*)(qkv + ((size_t)(b * N_ + n0 + nn)) * QKVS_ + 1024 + h * 64 + a8 * 8);
    uint4 vv1 = *(const uint4*)(qkv + ((size_t)(b * N_ + n0 + nn + 32)) * QKVS_ + 1024 + h * 64 + a8 * 8);
    __syncthreads();   // [A] prev reads done; kts/projs staged (vmcnt drained)
    // diag: 8 lanes per row, 2 passes for 64 rows (chunk permutation is sum-invariant)
#pragma unroll
    for (int pass = 0; pass < 2; pass++) {
      const int r = (tid >> 3) + pass * 32;
      short8 kv8 = *(const short8*)&kts[r * 64 + (tid & 7) * 8];
      const ushort* u = (const ushort*)&kv8;
      float s = 0.f;
#pragma unroll
      for (int j = 0; j < 8; j++) { float f = bf2f(u[j]); s += f * f; }
      s += __shfl_xor(s, 1);
      s += __shfl_xor(s, 2);
      s += __shfl_xor(s, 4);
      if ((tid & 7) == 0) diag_sh[r] = 0.0625f * s;
    }
    // v scatter into vsT[e][n]
    {
      const ushort* ve0 = (const ushort*)&vv0;
      const ushort* ve1 = (const ushort*)&vv1;
#pragma unroll
      for (int j = 0; j < 8; j++) {
        const int e = a8 * 8 + j;
        vsT[e][(((nn >> 3) ^ (e & 7)) << 3) | (nn & 7)] = ve0[j];
        vsT[e][((((nn + 32) >> 3) ^ (e & 7)) << 3) | (nn & 7)] = ve1[j];
      }
    }
    __syncthreads();   // [B] diag + vsT + kts visible
    // phi MFMA: out[m 64][n 64]; wave w -> m rows w*16..w*16+15
    floatx4 pacc[4] = {};
    const int ar = w * 16 + l16;
#pragma unroll
    for (int s = 0; s < 2; s++) {
      short8 af = *(const short8*)&projs[ar * 64 + ((s * 4 + quad) ^ (ar & 7)) * 8];
#pragma unroll
      for (int nj = 0; nj < 4; nj++) {
        const int br = nj * 16 + l16;
        short8 bf = *(const short8*)&kts[br * 64 + ((s * 4 + quad) ^ (br & 7)) * 8];
        pacc[nj] = __builtin_amdgcn_mfma_f32_16x16x32_bf16(af, bf, pacc[nj], 0, 0, 0);
      }
    }
    // FAVOR key epilogue -> kps
#pragma unroll
    for (int nj = 0; nj < 4; nj++) {
      const int n = nj * 16 + l16;
      const float dgn = diag_sh[n];
#pragma unroll
      for (int r = 0; r < 4; r++) {
        const int m = w * 16 + quad * 4 + r;
        float val = (m0 + m < M_) ? ratio * expf(dn * pacc[nj][r] - dgn + 1e-4f) : 0.f;
        kps[m][(((n >> 3) ^ (m & 7)) << 3) | (n & 7)] = f2bf(val);
      }
    }
    __syncthreads();   // [C] kps ready
    // ctx MFMA over k=n (2 steps)
    const int am = w * 16 + l16;
#pragma unroll
    for (int s = 0; s < 2; s++) {
      short8 af = *(const short8*)&kps[am][((s * 4 + quad) ^ (am & 7)) * 8];
#pragma unroll
      for (int et = 0; et < 4; et++) {
        const int be = et * 16 + l16;
        short8 bf = *(const short8*)&vsT[be][((s * 4 + quad) ^ (be & 7)) * 8];
        acc[et] = __builtin_amdgcn_mfma_f32_16x16x32_bf16(af, bf, acc[et], 0, 0, 0);
      }
    }
    // ksum partial: physical chunks kg and kg+4 of row km (union over threads = whole row)
#pragma unroll
    for (int cc = 0; cc < 2; cc++) {
      short8 kr = *(const short8*)&kps[km][(kg + cc * 4) * 8];
      const ushort* ku = (const ushort*)&kr;
#pragma unroll
      for (int j = 0; j < 8; j++) ksp += bf2f(ku[j]);
    }
  }
  float* pb = part + ((size_t)(bh * NS_ + ns) * 5 + mt) * 4096;
#pragma unroll
  for (int et = 0; et < 4; et++)
#pragma unroll
    for (int r = 0; r < 4; r++)
      pb[(w * 16 + quad * 4 + r) * 64 + et * 16 + l16] = acc[et][r];
  kshare[kg][km] = ksp;
  __syncthreads();
  if (tid < 64)
    kpart[((size_t)(bh * NS_ + ns) * 5 + mt) * 64 + tid] =
        kshare[0][tid] + kshare[1][tid] + kshare[2][tid] + kshare[3][tid];
}

// ---------------- reduce partials -> ctxbT bf16 [bh][64 e][320 m] + ksum[bh][PS_] ------------
__global__ __launch_bounds__(256) void ctx_reduce(const float* __restrict__ part,
                                                  const float* __restrict__ kpart,
                                                  ushort* __restrict__ ctxbT,
                                                  float* __restrict__ ksum) {
  const int bh = blockIdx.x, mt = blockIdx.y;
  const int tid = threadIdx.x;
  for (int idx = tid; idx < 4096; idx += 256) {
    float s = 0.f;
#pragma unroll
    for (int ns = 0; ns < NS_; ns++)
      s += part[((size_t)(bh * NS_ + ns) * 5 + mt) * 4096 + idx];
    int m = mt * 64 + (idx >> 6);
    int e = idx & 63;
    ctxbT[((size_t)bh * 64 + e) * 320 + m] = f2bf(s);   // m>=266 are zeros by construction
  }
  if (tid < 64) {
    float s = 0.f;
#pragma unroll
    for (int ns = 0; ns < NS_; ns++)
      s += kpart[((size_t)(bh * NS_ + ns) * 5 + mt) * 64 + tid];
    ksum[(size_t)bh * PS_ + mt * 64 + tid] = s;
  }
}

// ---------------- fused phi_q + dinv + attn_out (ctxbT staged via cp16) ----------------
__global__ __launch_bounds__(256) void attn_fused(const ushort* __restrict__ qkv,
                                                  const ushort* __restrict__ projp,
                                                  const ushort* __restrict__ ctxbT,
                                                  const float* __restrict__ ksum,
                                                  ushort* __restrict__ o) {
  __shared__ ushort As[64 * 64];      // q tile
  __shared__ ushort Bs[160 * 64];     // proj half
  __shared__ ushort qs[64][328];      // phi features (plain)
  __shared__ ushort cs[64 * 32];      // ctxbT chunk [64 e][32 m], XOR-4 chunks
  __shared__ float ks_sh[288];
  __shared__ float diag_sh[64], dsh[64];
  const int bh = blockIdx.x, b = bh >> 3, h = bh & 7;
  const int n0 = blockIdx.y * 64;
  const int tid = threadIdx.x;
  const int w = tid >> 6, lane = tid & 63, l16 = lane & 15, quad = lane >> 4;
  const int rl8 = lane >> 3;
  const int lc8 = ((lane & 7) ^ (rl8 & 7)) * 8;
#pragma unroll
  for (int j = 0; j < 2; j++) {
    const int rb = w * 16 + j * 8;
    async_cp16(qkv + (size_t)(b * N_ + n0 + rb + rl8) * QKVS_ + h * 64 + lc8, As + rb * 64);
  }
#pragma unroll
  for (int j = 0; j < 5; j++) {
    const int rb = w * 40 + j * 8;
    async_cp16(projp + (size_t)(rb + rl8) * 64 + lc8, Bs + rb * 64);
  }
  for (int i = tid; i < 288; i += 256) ks_sh[i] = ksum[(size_t)bh * PS_ + i];
  __syncthreads();
  {
    const int r = w * 16 + (lane >> 2);
    const int c0 = 2 * (lane & 3);
    float s = 0.f;
#pragma unroll
    for (int cc = 0; cc < 2; cc++) {
      short8 vv = *(const short8*)&As[r * 64 + ((c0 + cc) ^ (r & 7)) * 8];
      const ushort* u = (const ushort*)&vv;
#pragma unroll
      for (int j = 0; j < 8; j++) { float f = bf2f(u[j]); s += f * f; }
    }
    s += __shfl_xor(s, 1);
    s += __shfl_xor(s, 2);
    if ((lane & 3) == 0) diag_sh[r] = 0.0625f * s;
  }
  __syncthreads();
  floatx4 acc[18];
#pragma unroll
  for (int cf = 0; cf < 18; cf++) acc[cf] = (floatx4){0.f, 0.f, 0.f, 0.f};
  const int ar = w * 16 + l16;
#pragma unroll
  for (int s = 0; s < 2; s++) {
    short8 af = *(const short8*)&As[ar * 64 + ((s * 4 + quad) ^ (ar & 7)) * 8];
#pragma unroll
    for (int cf = 0; cf < 10; cf++) {
      const int br = cf * 16 + l16;
      short8 bf = *(const short8*)&Bs[br * 64 + ((s * 4 + quad) ^ (br & 7)) * 8];
      acc[cf] = __builtin_amdgcn_mfma_f32_16x16x32_bf16(af, bf, acc[cf], 0, 0, 0);
    }
  }
  __syncthreads();
#pragma unroll
  for (int j = 0; j < 4; j++) {
    const int rb = w * 32 + j * 8;
    async_cp16(projp + (size_t)(160 + rb + rl8) * 64 + lc8, Bs + rb * 64);
  }
  __syncthreads();
#pragma unroll
  for (int s = 0; s < 2; s++) {
    short8 af = *(const short8*)&As[ar * 64 + ((s * 4 + quad) ^ (ar & 7)) * 8];
#pragma unroll
    for (int cf = 10; cf < 18; cf++) {
      const int br = (cf - 10) * 16 + l16;
      short8 bf = *(const short8*)&Bs[br * 64 + ((s * 4 + quad) ^ (br & 7)) * 8];
      acc[cf] = __builtin_amdgcn_mfma_f32_16x16x32_bf16(af, bf, acc[cf], 0, 0, 0);
    }
  }
  const float dn = 0.35355339059327373f;
  const float ratio = 0.06131393394849658f;
#pragma unroll
  for (int r = 0; r < 4; r++) {
    const int row = w * 16 + quad * 4 + r;
    const float dg = diag_sh[row];
    float mx = -1e30f;
#pragma unroll
    for (int cf = 0; cf < 18; cf++) {
      const int col = cf * 16 + l16;
      if (col < M_) mx = fmaxf(mx, dn * acc[cf][r]);
    }
    mx = fmaxf(mx, __shfl_xor(mx, 1));
    mx = fmaxf(mx, __shfl_xor(mx, 2));
    mx = fmaxf(mx, __shfl_xor(mx, 4));
    mx = fmaxf(mx, __shfl_xor(mx, 8));
    float dacc = 0.f;
#pragma unroll
    for (int cf = 0; cf < 18; cf++) {
      const int col = cf * 16 + l16;
      float val = (col < M_) ? ratio * (expf(dn * acc[cf][r] - dg - mx) + 1e-4f) : 0.f;
      qs[row][col] = f2bf(val);
      dacc += val * ks_sh[col];
    }
    dacc += __shfl_xor(dacc, 1);
    dacc += __shfl_xor(dacc, 2);
    dacc += __shfl_xor(dacc, 4);
    dacc += __shfl_xor(dacc, 8);
    if (l16 == 0) dsh[row] = 1.f / (dacc + 1e-8f);
  }
  // phase B: o[n][e] = sum_m qs[n][m] * ctxbT[e][m]; stage cs via cp16 per 32-m chunk
  const int crl = lane >> 2;                       // e-row within 16
  const int clc = ((lane & 3) ^ ((lane >> 2) & 3)) * 8;   // source m-chunk (XOR-4)
  floatx4 acc2[4] = {};
  for (int m0 = 0; m0 < 288; m0 += 32) {
    __syncthreads();   // prev cs reads done (also covers qs writes on first iter)
    async_cp16(ctxbT + ((size_t)bh * 64 + w * 16 + crl) * 320 + m0 + clc, cs + (w * 16) * 32);
    __syncthreads();   // staged
    short8 af = *(const short8*)&qs[w * 16 + l16][m0 + quad * 8];
#pragma unroll
    for (int et = 0; et < 4; et++) {
      const int be = et * 16 + l16;
      short8 bf = *(const short8*)&cs[be * 32 + (quad ^ (be & 3)) * 8];
      acc2[et] = __builtin_amdgcn_mfma_f32_16x16x32_bf16(af, bf, acc2[et], 0, 0, 0);
    }
  }
#pragma unroll
  for (int r = 0; r < 4; r++) {
    const int nl = w * 16 + quad * 4 + r;
    const int n = n0 + nl;
    const float di = dsh[nl];
#pragma unroll
    for (int et = 0; et < 4; et++)
      o[((size_t)(b * N_ + n)) * 512 + h * 64 + et * 16 + l16] = f2bf(acc2[et][r] * di);
  }
}

// ---------------- depthwise conv K=31, pad 15, + bias + silu; bf16 in/out ----------------
#define TN_ 16
__global__ __launch_bounds__(256) void dwconv_kernel(const ushort* __restrict__ x,
                                                     const float* __restrict__ w,
                                                     const float* __restrict__ bias,
                                                     ushort* __restrict__ out) {
  const int bid = blockIdx.x;
  const int cb = bid & 3;
  const int nb = (bid >> 2) & 127;
  const int b  = bid >> 9;
  const int c = cb * 256 + threadIdx.x;
  const int n0 = nb * TN_;
  float win[TN_ + 30];
#pragma unroll
  for (int i = 0; i < TN_ + 30; i++) {
    int nn = n0 + i - 15;
    win[i] = (nn >= 0 && nn < N_) ? bf2f(x[(size_t)(b * N_ + nn) * INNER_ + c]) : 0.f;
  }
  float wc[31];
#pragma unroll
  for (int kk = 0; kk < 31; kk++) wc[kk] = w[c * 31 + kk];
  const float bsv = bias[c];
#pragma unroll
  for (int j = 0; j < TN_; j++) {
    float acc = bsv;
#pragma unroll
    for (int kk = 0; kk < 31; kk++) acc += win[j + kk] * wc[kk];
    acc = acc / (1.f + expf(-acc));
    out[(size_t)(b * N_ + n0 + j) * INNER_ + c] = f2bf(acc);
  }
}

// ---------------- host ----------------
extern "C" void kernel_launch(void* const* d_in, const int* in_sizes, int n_in,
                              void* d_out, int out_size, void* d_ws, size_t ws_size,
                              hipStream_t stream) {
  const float* in_x  = (const float*)d_in[0];
  const float* ln1_g = (const float*)d_in[1];
  const float* ln1_b = (const float*)d_in[2];
  const float* wq    = (const float*)d_in[3];
  const float* bq    = (const float*)d_in[4];
  const float* wk    = (const float*)d_in[5];
  const float* bk    = (const float*)d_in[6];
  const float* wv    = (const float*)d_in[7];
  const float* bv    = (const float*)d_in[8];
  const float* wo    = (const float*)d_in[9];
  const float* bo    = (const float*)d_in[10];
  const float* proj  = (const float*)d_in[11];
  const float* ln2_g = (const float*)d_in[12];
  const float* ln2_b = (const float*)d_in[13];
  const float* pw1_w = (const float*)d_in[14];
  const float* pw1_b = (const float*)d_in[15];
  const float* dw_w  = (const float*)d_in[16];
  const float* dw_b  = (const float*)d_in[17];
  const float* pw2_w = (const float*)d_in[18];
  const float* pw2_b = (const float*)d_in[19];

  char* cur = (char*)d_ws;
  auto alloc = [&](size_t bytes) { char* p = cur; cur += (bytes + 255) & ~(size_t)255; return p; };
  float*  x    = (float*)alloc((size_t)T_ * D_ * 4);
  ushort* p    = (ushort*)alloc((size_t)T_ * INNER_ * 2 * 2);      // glu+conv scratch
  float*  part = (float*)alloc((size_t)32 * NS_ * 5 * 4096 * 4);
  float*  kpart= (float*)alloc((size_t)32 * NS_ * 5 * 64 * 4);
  ushort* ctxbT= (ushort*)alloc((size_t)32 * 64 * 320 * 2);
  float*  ksum = (float*)alloc((size_t)32 * PS_ * 4);
  ushort* h    = (ushort*)alloc((size_t)T_ * D_ * 2);
  ushort* qkv  = (ushort*)alloc((size_t)T_ * QKVS_ * 2);
  ushort* obuf = (ushort*)alloc((size_t)T_ * D_ * 2);
  ushort* wqkv_b = (ushort*)alloc((size_t)L_LAYERS * QKVS_ * 512 * 2);
  float*  bqkv   = (float*)alloc((size_t)L_LAYERS * QKVS_ * 4);
  ushort* wo_b = (ushort*)alloc((size_t)L_LAYERS * D_ * D_ * 2);
  ushort* pjp  = (ushort*)alloc((size_t)L_LAYERS * 320 * 64 * 2);
  ushort* p1_b = (ushort*)alloc((size_t)L_LAYERS * 2048 * D_ * 2);
  float*  pb1  = (float*)alloc((size_t)L_LAYERS * 2048 * 4);
  ushort* p2_b = (ushort*)alloc((size_t)L_LAYERS * D_ * INNER_ * 2);
  ushort* glu  = p;
  ushort* conv = p + (size_t)T_ * INNER_;

  pack_qkv_w<<<(L_LAYERS * 512 * 128 + 255) / 256, 256, 0, stream>>>((const float4*)wq, wqkv_b, 0);
  pack_qkv_w<<<(L_LAYERS * 512 * 128 + 255) / 256, 256, 0, stream>>>((const float4*)wk, wqkv_b, 512);
  pack_qkv_w<<<(L_LAYERS * 512 * 128 + 255) / 256, 256, 0, stream>>>((const float4*)wv, wqkv_b, 1024);
  pack_qkv_b<<<(L_LAYERS * QKVS_ + 255) / 256, 256, 0, stream>>>(bq, bk, bv, bqkv);
  pad_proj<<<(L_LAYERS * 320 * 64 + 255) / 256, 256, 0, stream>>>(proj, pjp);
  pack_pw1_w<<<(L_LAYERS * 2048 * 128 + 255) / 256, 256, 0, stream>>>((const float4*)pw1_w, p1_b);
  pack_pw1_b<<<(L_LAYERS * 2048 + 255) / 256, 256, 0, stream>>>(pw1_b, pb1);
  {
    int n4 = L_LAYERS * D_ * D_ / 4;
    f2bf4_kernel<<<(n4 + 255) / 256, 256, 0, stream>>>((const float4*)wo, wo_b, n4);
    n4 = L_LAYERS * D_ * INNER_ / 4;
    f2bf4_kernel<<<(n4 + 255) / 256, 256, 0, stream>>>((const float4*)pw2_w, p2_b, n4);
  }

  for (int l = 0; l < L_LAYERS; l++) {
    const ushort* wqkvl = wqkv_b + (size_t)l * QKVS_ * 512;
    const ushort* wol = wo_b + (size_t)l * D_ * D_;
    const ushort* pjl = pjp + (size_t)l * 320 * 64;
    const ushort* p1l = p1_b + (size_t)l * 2048 * D_;
    const ushort* p2l = p2_b + (size_t)l * D_ * INNER_;
    const float*  dwl = dw_w + (size_t)l * INNER_ * 31;
    const float*  xin = (l == 0) ? in_x : x;
    float* xout = (l == L_LAYERS - 1) ? (float*)d_out : x;

    ln_kernel<<<T_, 256, 0, stream>>>(xin, ln1_g + l * D_, ln1_b + l * D_, h);
    gemm_mfma<false, true, 0, 128><<<dim3(T_ / 128, QKVS_ / 128), 256, 0, stream>>>(
        h, wqkvl, bqkv + (size_t)l * QKVS_, nullptr, qkv, D_, QKVS_);
    ctx_phi_mfma<<<dim3(32, 5, NS_), 256, 0, stream>>>(qkv, pjl, part, kpart);
    ctx_reduce<<<dim3(32, 5), 256, 0, stream>>>(part, kpart, ctxbT, ksum);
    attn_fused<<<dim3(32, 32), 256, 0, stream>>>(qkv, pjl, ctxbT, ksum, obuf);
    gemm_mfma<true, false, 0, 64><<<dim3(T_ / 128, 8), 256, 0, stream>>>(
        obuf, wol, bo + l * D_, xin, x, D_, D_);
    ln_kernel<<<T_, 256, 0, stream>>>(x, ln2_g + l * D_, ln2_b + l * D_, h);
    gemm_mfma<false, true, 1, 128><<<dim3(T_ / 128, 16), 256, 0, stream>>>(
        h, p1l, pb1 + (size_t)l * 2048, nullptr, glu, D_, INNER_);
    dwconv_kernel<<<B_ * (N_ / TN_) * 4, 256, 0, stream>>>(glu, dwl, dw_b + l * INNER_, conv);
    gemm_mfma<true, false, 0, 64><<<dim3(T_ / 128, 8), 256, 0, stream>>>(
        conv, p2l, pw2_b + l * D_, x, xout, INNER_, D_);
  }
}